// Round 3
// baseline (624.132 us; speedup 1.0000x reference)
//
#include <hip/hip_runtime.h>

// SAN Subtraction: out[n,c,kh*7+kw, h*112+w] = x[n,c,h,w] - x[n,c,refl(h+kh-3),refl(w+kw-3)]
// x (4,64,112,112) fp32, reflect padding (jnp 'reflect': t<0 -> -t ; t>D-1 -> 2(D-1)-t).
//
// Round 3 probe: minimize read-side pressure. LDS-staged plane + REGISTER WINDOW:
// win[10] built once per (kh,row) with 10 scalar LDS reads, amortized over the 7 kw
// stores (1.43 scalar reads/store vs round-2's 4). Plain vf4 stores. If this doesn't
// move dur_us, every non-store pipe is <30% loaded across 4 distinct kernels and the
// kernel is at the write roofline (~104 us); residual belongs to the harness.

#define NC_   256      // N*C
#define H_    112
#define W_    112
#define K_    7
#define PADV  3
#define HW    12544    // H*W
#define K2_   49

typedef float vf4 __attribute__((ext_vector_type(4)));

__global__ __launch_bounds__(448) void san_sub_kernel(const float* __restrict__ x,
                                                      float* __restrict__ out) {
    __shared__ float sx[HW];            // 50176 B: one full (n,c) plane; 3 blocks/CU

    const int bid = blockIdx.x;
    const int nc  = bid / K_;           // consecutive blocks share nc -> L2/L3 read reuse
    const int kh  = bid % K_;
    const int tid = threadIdx.x;        // 0..447 (7 waves)

    const float* __restrict__ xc = x + (size_t)nc * HW;

    // stage full plane into LDS: 3136 vf4 by 448 threads, 7 each, lane-contiguous
    #pragma unroll
    for (int s = 0; s < 7; ++s) {
        int idx = s * 448 + tid;
        vf4 v = *reinterpret_cast<const vf4*>(xc + idx * 4);
        *reinterpret_cast<vf4*>(&sx[idx * 4]) = v;
    }
    __syncthreads();

    const int trow = tid / 28;          // 0..15
    const int w4   = tid % 28;
    const int w    = w4 * 4;

    float* __restrict__ pbase = out + (size_t)(nc * K2_ + kh * K_) * HW + w;

    #pragma unroll
    for (int i = 0; i < 7; ++i) {
        const int h = i * 16 + trow;    // covers 0..111 exactly once per block
        int r = h + kh - PADV;          // reflected source row
        r = (r < 0) ? -r : r;
        r = (r > H_-1) ? (2*(H_-1) - r) : r;
        const float* __restrict__ srow = &sx[r * W_];

        vf4 center = *reinterpret_cast<const vf4*>(&sx[h * W_ + w]);

        // 10-float register window covering columns [w-3, w+6], reflect-clamped.
        // Built ONCE per (kh,row): 10 scalar LDS reads amortized over 7 stores.
        float win[10];
        #pragma unroll
        for (int t = 0; t < 10; ++t) {
            int col = w - PADV + t;
            col = (col < 0) ? -col : col;
            col = (col > W_-1) ? (2*(W_-1) - col) : col;
            win[t] = srow[col];
        }

        float* __restrict__ po = pbase + h * W_;
        #pragma unroll
        for (int kw = 0; kw < K_; ++kw) {
            vf4 o;
            o.x = center.x - win[kw + 0];
            o.y = center.y - win[kw + 1];
            o.z = center.z - win[kw + 2];
            o.w = center.w - win[kw + 3];
            *reinterpret_cast<vf4*>(po + (size_t)kw * HW) = o;   // plain store
        }
    }
}

extern "C" void kernel_launch(void* const* d_in, const int* in_sizes, int n_in,
                              void* d_out, int out_size, void* d_ws, size_t ws_size,
                              hipStream_t stream) {
    const float* x = (const float*)d_in[0];
    float* out = (float*)d_out;
    dim3 grid(NC_ * K_);   // (nc, kh)
    dim3 block(448);       // 7 waves
    san_sub_kernel<<<grid, block, 0, stream>>>(x, out);
}